// Round 2
// baseline (522.535 us; speedup 1.0000x reference)
//
#include <hip/hip_runtime.h>

#define N_HID 128

// ---------------------------------------------------------------------------
// Fused dual GEMM: msg = h @ We^T ; out = h @ Ws^T + b
// No LDS: W is 64KB, k-slices are L1-resident (2KB/slice), h rows coalesce.
// 256 threads, 64 rows/block, per-thread tile 4 rows x 8 cols.
// ---------------------------------------------------------------------------
__global__ __launch_bounds__(256) void gemm_dual(
    const float* __restrict__ h,
    const float* __restrict__ We,
    const float* __restrict__ Ws,
    const float* __restrict__ bs,
    float* __restrict__ msg,
    float* __restrict__ outSelf,
    int n)
{
    const int t    = threadIdx.x;
    const int rg   = t >> 4;   // 0..15
    const int jg   = t & 15;   // 0..15
    const int row0 = blockIdx.x * 64;

    int  rows[4];
    bool rv[4];
    int  rc[4];
#pragma unroll
    for (int i = 0; i < 4; ++i) {
        rows[i] = row0 + rg + 16 * i;
        rv[i]   = rows[i] < n;
        rc[i]   = rv[i] ? rows[i] : (n - 1);   // clamp: load valid memory, never store
    }

    float acc[4][8];

    // ---- pass 1: msg = h @ We^T ----
#pragma unroll
    for (int i = 0; i < 4; ++i)
#pragma unroll
        for (int j = 0; j < 8; ++j) acc[i][j] = 0.f;

#pragma unroll 4
    for (int k = 0; k < N_HID; k += 4) {
        float4 a[4], w[8];
#pragma unroll
        for (int i = 0; i < 4; ++i)
            a[i] = *(const float4*)&h[rc[i] * N_HID + k];
#pragma unroll
        for (int j = 0; j < 8; ++j)
            w[j] = *(const float4*)&We[(jg + 16 * j) * N_HID + k];
#pragma unroll
        for (int i = 0; i < 4; ++i)
#pragma unroll
            for (int j = 0; j < 8; ++j)
                acc[i][j] += a[i].x * w[j].x + a[i].y * w[j].y
                           + a[i].z * w[j].z + a[i].w * w[j].w;
    }
#pragma unroll
    for (int i = 0; i < 4; ++i) if (rv[i]) {
#pragma unroll
        for (int j = 0; j < 8; ++j)
            msg[rows[i] * N_HID + jg + 16 * j] = acc[i][j];
    }

    // ---- pass 2: outSelf = h @ Ws^T + b ----
#pragma unroll
    for (int i = 0; i < 4; ++i)
#pragma unroll
        for (int j = 0; j < 8; ++j) acc[i][j] = 0.f;

#pragma unroll 4
    for (int k = 0; k < N_HID; k += 4) {
        float4 a[4], w[8];
#pragma unroll
        for (int i = 0; i < 4; ++i)
            a[i] = *(const float4*)&h[rc[i] * N_HID + k];
#pragma unroll
        for (int j = 0; j < 8; ++j)
            w[j] = *(const float4*)&Ws[(jg + 16 * j) * N_HID + k];
#pragma unroll
        for (int i = 0; i < 4; ++i)
#pragma unroll
            for (int j = 0; j < 8; ++j)
                acc[i][j] += a[i].x * w[j].x + a[i].y * w[j].y
                           + a[i].z * w[j].z + a[i].w * w[j].w;
    }

    float bb[8];
#pragma unroll
    for (int j = 0; j < 8; ++j) bb[j] = bs[jg + 16 * j];

#pragma unroll
    for (int i = 0; i < 4; ++i) if (rv[i]) {
#pragma unroll
        for (int j = 0; j < 8; ++j)
            outSelf[rows[i] * N_HID + jg + 16 * j] = acc[i][j] + bb[j];
    }
}

// ---------------------------------------------------------------------------
// Degree count: 800k int atomics over 50k counters.
// ---------------------------------------------------------------------------
__global__ void count_deg(const int* __restrict__ dst, int* __restrict__ deg, int E)
{
    int e = blockIdx.x * blockDim.x + threadIdx.x;
    if (e < E) atomicAdd(&deg[dst[e]], 1);
}

// ---------------------------------------------------------------------------
// Single-block exclusive scan of deg -> offs (and cursor copy). 1024 threads,
// wave shuffle-scan + 16-wave-sum scan.
// ---------------------------------------------------------------------------
__global__ __launch_bounds__(1024) void scan_deg(
    const int* __restrict__ deg, int* __restrict__ offs, int* __restrict__ cursor, int n)
{
    __shared__ int wsum[16];
    const int t    = threadIdx.x;
    const int lane = t & 63;
    const int wid  = t >> 6;
    int carry = 0;

    for (int base = 0; base < n; base += 1024) {
        int idx = base + t;
        int v   = (idx < n) ? deg[idx] : 0;
        int val = v;
#pragma unroll
        for (int off = 1; off < 64; off <<= 1) {
            int y = __shfl_up(val, off);
            if (lane >= off) val += y;
        }
        if (lane == 63) wsum[wid] = val;
        __syncthreads();
        if (wid == 0 && lane < 16) {
            int s = wsum[lane];
#pragma unroll
            for (int off = 1; off < 16; off <<= 1) {
                int y = __shfl_up(s, off);
                if (lane >= off) s += y;
            }
            wsum[lane] = s;
        }
        __syncthreads();
        int wprefix = (wid > 0) ? wsum[wid - 1] : 0;
        int excl    = carry + wprefix + val - v;
        if (idx < n) { offs[idx] = excl; cursor[idx] = excl; }
        carry += wsum[15];
        __syncthreads();   // protect wsum before next chunk overwrites
    }
    if (t == 0) offs[n] = carry;
}

// ---------------------------------------------------------------------------
// CSR fill: pos = cursor[dst]++ ; csr[pos] = src.
// ---------------------------------------------------------------------------
__global__ void scatter_edges(const int* __restrict__ src,
                              const int* __restrict__ dst,
                              int* __restrict__ cursor, int* __restrict__ csr, int E)
{
    int e = blockIdx.x * blockDim.x + threadIdx.x;
    if (e < E) {
        int d   = dst[e];
        int pos = atomicAdd(&cursor[d], 1);
        csr[pos] = src[e];
    }
}

// ---------------------------------------------------------------------------
// Per-node gather + mean + self + relu. One wave per node, float2 per lane.
// out already holds self part (h@Ws^T+b); update in place.
// ---------------------------------------------------------------------------
__global__ __launch_bounds__(256) void gather_finish(
    const int* __restrict__ offs,
    const int* __restrict__ csr,
    const float* __restrict__ msg,
    float* __restrict__ out,
    int n)
{
    int node = blockIdx.x * 4 + (threadIdx.x >> 6);
    if (node >= n) return;
    int lane  = threadIdx.x & 63;
    int start = offs[node];
    int end   = offs[node + 1];

    const float2* m2 = (const float2*)msg;
    float ax = 0.f, ay = 0.f;
    int i = start;
    for (; i + 4 <= end; i += 4) {
        int s0 = csr[i + 0], s1 = csr[i + 1], s2 = csr[i + 2], s3 = csr[i + 3];
        float2 v0 = m2[(size_t)s0 * 64 + lane];
        float2 v1 = m2[(size_t)s1 * 64 + lane];
        float2 v2 = m2[(size_t)s2 * 64 + lane];
        float2 v3 = m2[(size_t)s3 * 64 + lane];
        ax += v0.x + v1.x + v2.x + v3.x;
        ay += v0.y + v1.y + v2.y + v3.y;
    }
    for (; i < end; ++i) {
        int s = csr[i];
        float2 v = m2[(size_t)s * 64 + lane];
        ax += v.x; ay += v.y;
    }

    int   d  = end - start;
    float sc = d > 0 ? 1.0f / (float)d : 0.f;

    float2* o2 = (float2*)out;
    float2 sv  = o2[(size_t)node * 64 + lane];
    float2 r;
    r.x = fmaxf(sv.x + ax * sc, 0.f);
    r.y = fmaxf(sv.y + ay * sc, 0.f);
    o2[(size_t)node * 64 + lane] = r;
}

// ---------------------------------------------------------------------------
extern "C" void kernel_launch(void* const* d_in, const int* in_sizes, int n_in,
                              void* d_out, int out_size, void* d_ws, size_t ws_size,
                              hipStream_t stream)
{
    const float* h   = (const float*)d_in[0];
    const int*   src = (const int*)d_in[1];   // harness passes integer inputs as int32
    const int*   dst = (const int*)d_in[2];
    const float* We  = (const float*)d_in[3];
    const float* Ws  = (const float*)d_in[4];
    const float* bs  = (const float*)d_in[5];
    float*       out = (float*)d_out;

    const int n = in_sizes[0] / N_HID;   // 50000
    const int E = in_sizes[1];           // 800000

    // workspace layout (~29.4 MB)
    float* msg    = (float*)d_ws;                       // n*128 f32
    int*   deg    = (int*)(msg + (size_t)n * N_HID);    // n
    int*   offs   = deg + n;                            // n+1
    int*   cursor = offs + (n + 8);                     // n
    int*   csr    = cursor + n;                         // E

    hipMemsetAsync(deg, 0, sizeof(int) * (size_t)n, stream);
    count_deg<<<(E + 255) / 256, 256, 0, stream>>>(dst, deg, E);
    gemm_dual<<<(n + 63) / 64, 256, 0, stream>>>(h, We, Ws, bs, msg, out, n);
    scan_deg<<<1, 1024, 0, stream>>>(deg, offs, cursor, n);
    scatter_edges<<<(E + 255) / 256, 256, 0, stream>>>(src, dst, cursor, csr, E);
    gather_finish<<<(n + 3) / 4, 256, 0, stream>>>(offs, csr, msg, out, n);
}